// Round 1
// baseline (546.175 us; speedup 1.0000x reference)
//
#include <hip/hip_runtime.h>

#define D_IN_C 16
#define D_OUT_C 32

// ---------------------------------------------------------------------------
// K1: h = relu(x@w1+b1)@w2+b2 ; zero cnt (and summed, fallback path only).
// ---------------------------------------------------------------------------
__global__ __launch_bounds__(256) void mlp_kernel(
    const float* __restrict__ x,
    const float* __restrict__ w1, const float* __restrict__ b1,
    const float* __restrict__ w2, const float* __restrict__ b2,
    float* __restrict__ h, float* __restrict__ summed, int* __restrict__ cnt,
    int n_nodes) {
  __shared__ float sw1[256];
  __shared__ float sw2[256];
  __shared__ float sb1[16];
  __shared__ float sb2[16];
  int t = threadIdx.x;
  sw1[t] = w1[t];
  sw2[t] = w2[t];
  if (t < 16) { sb1[t] = b1[t]; sb2[t] = b2[t]; }
  __syncthreads();

  int n = blockIdx.x * blockDim.x + t;
  if (n >= n_nodes) return;

  float xi[16];
  const float4* xr = (const float4*)(x + (size_t)n * 16);
  float4 v0 = xr[0], v1 = xr[1], v2 = xr[2], v3 = xr[3];
  xi[0]=v0.x; xi[1]=v0.y; xi[2]=v0.z; xi[3]=v0.w;
  xi[4]=v1.x; xi[5]=v1.y; xi[6]=v1.z; xi[7]=v1.w;
  xi[8]=v2.x; xi[9]=v2.y; xi[10]=v2.z; xi[11]=v2.w;
  xi[12]=v3.x; xi[13]=v3.y; xi[14]=v3.z; xi[15]=v3.w;

  float t1[16];
#pragma unroll
  for (int j = 0; j < 16; ++j) {
    float acc = sb1[j];
#pragma unroll
    for (int k = 0; k < 16; ++k) acc += xi[k] * sw1[k * 16 + j];
    t1[j] = fmaxf(acc, 0.0f);
  }
  float hh[16];
#pragma unroll
  for (int j = 0; j < 16; ++j) {
    float acc = sb2[j];
#pragma unroll
    for (int k = 0; k < 16; ++k) acc += t1[k] * sw2[k * 16 + j];
    hh[j] = acc;
  }

  float4* hw = (float4*)(h + (size_t)n * 16);
  hw[0] = make_float4(hh[0], hh[1], hh[2], hh[3]);
  hw[1] = make_float4(hh[4], hh[5], hh[6], hh[7]);
  hw[2] = make_float4(hh[8], hh[9], hh[10], hh[11]);
  hw[3] = make_float4(hh[12], hh[13], hh[14], hh[15]);

  cnt[n] = 0;  // ws is poisoned before every launch
  if (summed) {
    float4* sz = (float4*)(summed + (size_t)n * 16);
    float4 z = make_float4(0.f, 0.f, 0.f, 0.f);
    sz[0] = z; sz[1] = z; sz[2] = z; sz[3] = z;
  }
}

// ---------------------------------------------------------------------------
// NEW PATH: counting-sort by dst, then gather-aggregate (no f32 atomics).
// ---------------------------------------------------------------------------

// K2: histogram of destinations.
__global__ __launch_bounds__(256) void hist_kernel(
    const int* __restrict__ dst, int* __restrict__ cnt, int n_edges) {
  int e = blockIdx.x * 256 + threadIdx.x;
  if (e < n_edges) atomicAdd(&cnt[dst[e]], 1);
}

// K3a: per-block inclusive scan of cnt -> intra (excl-within-block) + blocksum.
__global__ __launch_bounds__(256) void scan_a_kernel(
    const int* __restrict__ cnt, int* __restrict__ intra,
    int* __restrict__ blocksum, int n_nodes) {
  __shared__ int s[256];
  int t = threadIdx.x;
  int i = blockIdx.x * 256 + t;
  int c = (i < n_nodes) ? cnt[i] : 0;
  s[t] = c;
  __syncthreads();
#pragma unroll
  for (int off = 1; off < 256; off <<= 1) {
    int add = (t >= off) ? s[t - off] : 0;
    __syncthreads();
    s[t] += add;
    __syncthreads();
  }
  if (i < n_nodes) intra[i] = s[t] - c;  // exclusive within block
  if (t == 255) blocksum[blockIdx.x] = s[255];
}

// K3b: single-block exclusive scan of block sums (nblk <= 512).
__global__ __launch_bounds__(512) void scan_b_kernel(
    const int* __restrict__ blocksum, int* __restrict__ blockoff, int nblk) {
  __shared__ int s[512];
  int t = threadIdx.x;
  int v = (t < nblk) ? blocksum[t] : 0;
  s[t] = v;
  __syncthreads();
#pragma unroll
  for (int off = 1; off < 512; off <<= 1) {
    int add = (t >= off) ? s[t - off] : 0;
    __syncthreads();
    s[t] += add;
    __syncthreads();
  }
  if (t < nblk) blockoff[t] = s[t] - v;  // exclusive
}

// K3c: cursor[i] = global exclusive scan = start offset of node i.
__global__ __launch_bounds__(256) void scan_c_kernel(
    const int* __restrict__ intra, const int* __restrict__ blockoff,
    int* __restrict__ cursor, int n_nodes) {
  int i = blockIdx.x * 256 + threadIdx.x;
  if (i < n_nodes) cursor[i] = intra[i] + blockoff[blockIdx.x];
}

// K4: bin edges by destination: esrc[start[d]..end[d]) = src of d's in-edges.
// After this kernel cursor[d] == end[d].
__global__ __launch_bounds__(256) void bin_kernel(
    const int* __restrict__ src, const int* __restrict__ dst,
    int* __restrict__ cursor, int* __restrict__ esrc, int n_edges) {
  int e = blockIdx.x * 256 + threadIdx.x;
  if (e < n_edges) {
    int d = dst[e];
    int p = atomicAdd(&cursor[d], 1);
    esrc[p] = src[e];
  }
}

// K5: aggregate + fused SAGE epilogue. 16 threads per node.
// out = (sum(h[src])/max(cnt,1)) @ wl + bl + h @ wr
__global__ __launch_bounds__(256) void agg_out_kernel(
    const float* __restrict__ h, const int* __restrict__ esrc,
    const int* __restrict__ cursor, const int* __restrict__ cnt,
    const float* __restrict__ wl, const float* __restrict__ bl,
    const float* __restrict__ wr, float* __restrict__ out, int n_nodes) {
  __shared__ float swl[512];
  __shared__ float swr[512];
  __shared__ float sbl[32];
  int t = threadIdx.x;
  for (int i = t; i < 512; i += 256) { swl[i] = wl[i]; swr[i] = wr[i]; }
  if (t < 32) sbl[t] = bl[t];
  __syncthreads();

  int n = blockIdx.x * 16 + (t >> 4);
  int k = t & 15;
  if (n >= n_nodes) return;

  int end = cursor[n];
  int c = cnt[n];
  int p = end - c;  // start

  float sum = 0.0f;
  // full chunks of 16 edges: one coalesced esrc load, shfl-broadcast,
  // 16 independent L2-resident gathers (no dependent-load chain).
  while (end - p >= 16) {
    int ev = esrc[p + k];
#pragma unroll
    for (int kk = 0; kk < 16; ++kk) {
      int s = __shfl(ev, kk, 16);
      sum += h[s * 16 + k];
    }
    p += 16;
  }
  int m = end - p;
  if (m > 0) {
    int ev = (k < m) ? esrc[p + k] : 0;
    for (int kk = 0; kk < m; ++kk) {
      int s = __shfl(ev, kk, 16);
      sum += h[s * 16 + k];
    }
  }

  float mean = sum / fmaxf((float)c, 1.0f);
  float hk = h[n * 16 + k];

  float acc0 = sbl[k];
  float acc1 = sbl[k + 16];
#pragma unroll
  for (int kk = 0; kk < 16; ++kk) {
    float mv = __shfl(mean, kk, 16);
    float hv = __shfl(hk, kk, 16);
    acc0 += mv * swl[kk * 32 + k]      + hv * swr[kk * 32 + k];
    acc1 += mv * swl[kk * 32 + k + 16] + hv * swr[kk * 32 + k + 16];
  }
  out[(size_t)n * 32 + k]      = acc0;
  out[(size_t)n * 32 + 16 + k] = acc1;
}

// ---------------------------------------------------------------------------
// FALLBACK PATH (previous verified kernels) — used if ws_size is too small.
// ---------------------------------------------------------------------------
__global__ __launch_bounds__(256) void scatter_kernel(
    const int* __restrict__ src, const int* __restrict__ dst,
    const float* __restrict__ h, float* __restrict__ summed,
    int* __restrict__ cnt, long long n_edges) {
  long long tid = (long long)blockIdx.x * blockDim.x + threadIdx.x;
  long long e = tid >> 4;
  int k = (int)(tid & 15);
  if (e >= n_edges) return;
  int s = src[e];
  int d = dst[e];
  float val = h[(size_t)s * 16 + k];
  atomicAdd(&summed[(size_t)d * 16 + k], val);
  if (k == 0) atomicAdd(&cnt[d], 1);
}

__global__ __launch_bounds__(256) void out_kernel(
    const float* __restrict__ h, const float* __restrict__ summed,
    const int* __restrict__ cnt,
    const float* __restrict__ wl, const float* __restrict__ bl,
    const float* __restrict__ wr, float* __restrict__ out, int n_nodes) {
  __shared__ float swl[512];
  __shared__ float swr[512];
  __shared__ float sbl[32];
  int t = threadIdx.x;
  for (int i = t; i < 512; i += 256) { swl[i] = wl[i]; swr[i] = wr[i]; }
  if (t < 32) sbl[t] = bl[t];
  __syncthreads();

  int gid = blockIdx.x * 256 + t;
  int n = gid >> 5;
  int j = gid & 31;
  if (n >= n_nodes) return;

  float inv = 1.0f / fmaxf((float)cnt[n], 1.0f);
  const float* hr = h + (size_t)n * 16;
  const float* sr = summed + (size_t)n * 16;
  float acc = sbl[j];
#pragma unroll
  for (int k = 0; k < 16; ++k) {
    acc += sr[k] * inv * swl[k * 32 + j] + hr[k] * swr[k * 32 + j];
  }
  out[(size_t)n * 32 + j] = acc;
}

// ---------------------------------------------------------------------------
extern "C" void kernel_launch(void* const* d_in, const int* in_sizes, int n_in,
                              void* d_out, int out_size, void* d_ws, size_t ws_size,
                              hipStream_t stream) {
  const float* x  = (const float*)d_in[0];
  const int* eidx = (const int*)d_in[1];
  const float* w1 = (const float*)d_in[2];
  const float* b1 = (const float*)d_in[3];
  const float* w2 = (const float*)d_in[4];
  const float* b2 = (const float*)d_in[5];
  const float* wl = (const float*)d_in[6];
  const float* bl = (const float*)d_in[7];
  const float* wr = (const float*)d_in[8];
  float* out = (float*)d_out;

  const int n_nodes = in_sizes[0] / D_IN_C;             // 100000
  const long long n_edges = (long long)in_sizes[1] / 2; // 3200000
  const int* src = eidx;
  const int* dst = eidx + n_edges;

  const int node_blocks = (n_nodes + 255) / 256;         // 391
  const int edge_blocks = (int)((n_edges + 255) / 256);  // 12500

  // New-path workspace layout.
  float* h        = (float*)d_ws;                        // N*16 f32
  int*   cnt      = (int*)(h + (size_t)n_nodes * 16);    // N
  int*   cursor   = cnt + n_nodes;                       // N
  int*   intra    = cursor + n_nodes;                    // N
  int*   blocksum = intra + n_nodes;                     // <=1024
  int*   blockoff = blocksum + 1024;                     // <=1024
  int*   esrc     = blockoff + 1024;                     // E

  size_t need = ((size_t)n_nodes * 16 + 3ull * n_nodes + 2048 + (size_t)n_edges)
                * sizeof(float);

  if (ws_size >= need && node_blocks <= 512) {
    // ---- counting-sort path (no f32 atomics) ----
    mlp_kernel<<<node_blocks, 256, 0, stream>>>(x, w1, b1, w2, b2, h,
                                                nullptr, cnt, n_nodes);
    hist_kernel<<<edge_blocks, 256, 0, stream>>>(dst, cnt, (int)n_edges);
    scan_a_kernel<<<node_blocks, 256, 0, stream>>>(cnt, intra, blocksum, n_nodes);
    scan_b_kernel<<<1, 512, 0, stream>>>(blocksum, blockoff, node_blocks);
    scan_c_kernel<<<node_blocks, 256, 0, stream>>>(intra, blockoff, cursor, n_nodes);
    bin_kernel<<<edge_blocks, 256, 0, stream>>>(src, dst, cursor, esrc, (int)n_edges);
    {
      int blocks = (n_nodes + 15) / 16;
      agg_out_kernel<<<blocks, 256, 0, stream>>>(h, esrc, cursor, cnt,
                                                 wl, bl, wr, out, n_nodes);
    }
  } else {
    // ---- fallback: previous verified atomic path ----
    float* summed = h + (size_t)n_nodes * 16;
    int*   fcnt   = (int*)(summed + (size_t)n_nodes * 16);
    mlp_kernel<<<node_blocks, 256, 0, stream>>>(x, w1, b1, w2, b2, h,
                                                summed, fcnt, n_nodes);
    {
      long long total = n_edges * 16;
      int blocks = (int)((total + 255) / 256);
      scatter_kernel<<<blocks, 256, 0, stream>>>(src, dst, h, summed, fcnt, n_edges);
    }
    {
      long long total = (long long)n_nodes * 32;
      int blocks = (int)((total + 255) / 256);
      out_kernel<<<blocks, 256, 0, stream>>>(h, summed, fcnt, wl, bl, wr, out, n_nodes);
    }
  }
}